// Round 4
// baseline (381.483 us; speedup 1.0000x reference)
//
#include <hip/hip_runtime.h>
#include <hip/hip_bf16.h>
#include <math.h>

#define SS   1024
#define DM   1024
#define NH   16
#define DKH  64
#define NB   4
#define NBH  64

typedef unsigned short ush;
typedef __attribute__((ext_vector_type(8))) short bf8_t;   // 8 bf16 = 4 VGPR
typedef __attribute__((ext_vector_type(4))) float f32x4;
#define MFMA16(a,b,c) __builtin_amdgcn_mfma_f32_16x16x32_bf16((a),(b),(c),0,0,0)

__device__ __forceinline__ ush f2bf(float x){
  return __bfloat16_as_ushort(__float2bfloat16(x));
}
__device__ __forceinline__ float bf2f(ush h){
  return __bfloat162float(__ushort_as_bfloat16(h));
}
__device__ __forceinline__ unsigned int pk2(float a, float b){
  return (unsigned int)f2bf(a) | ((unsigned int)f2bf(b) << 16);
}
// [64][64]-ush tile, XOR swizzle on 16B chunks: uniform bank-quad spread
__device__ __forceinline__ int swz8(int row, int chunk){
  return row*64 + (((chunk) ^ (row & 7)) << 3);
}

// ---- fused weight convert: W (K x N) fp32 -> Wt (N x K) bf16 hi (+lo for z<3)
__global__ void wconv4(const float* __restrict__ W0, const float* __restrict__ W1,
                       const float* __restrict__ W2, const float* __restrict__ W3,
                       ush* __restrict__ H0, ush* __restrict__ H1,
                       ush* __restrict__ H2, ush* __restrict__ H3,
                       ush* __restrict__ L0, ush* __restrict__ L1,
                       ush* __restrict__ L2)
{
  __shared__ float T[32][33];
  const int tx = threadIdx.x, ty = threadIdx.y;    // (32,8)
  const int z = blockIdx.z;
  const float* W = (z==0)?W0:(z==1)?W1:(z==2)?W2:W3;
  ush* H = (z==0)?H0:(z==1)?H1:(z==2)?H2:H3;
  ush* L = (z==0)?L0:(z==1)?L1:(z==2)?L2:nullptr;
  const int k0 = blockIdx.y*32, n0 = blockIdx.x*32;
  #pragma unroll
  for (int i = 0; i < 4; ++i){
    int r = ty + 8*i;
    T[r][tx] = W[(size_t)(k0 + r)*DM + n0 + tx];
  }
  __syncthreads();
  #pragma unroll
  for (int i = 0; i < 4; ++i){
    int r = ty + 8*i;              // n-local
    float v = T[tx][r];
    ush hh = f2bf(v);
    H[(size_t)(n0 + r)*DM + k0 + tx] = hh;
    if (z < 3) L[(size_t)(n0 + r)*DM + k0 + tx] = f2bf(v - bf2f(hh));
  }
}

// ---- fused Q/K/V projection: z selects input/weights/output.
// C = A @ (Wh + Wl)^T + bias  (2-term split-B), 128x128 tile, reg-prefetch.
__global__ __launch_bounds__(256) void proj_qkv(
    const float* __restrict__ Aq, const float* __restrict__ Ak,
    const float* __restrict__ Av,
    const ush* __restrict__ Wqh, const ush* __restrict__ Wql,
    const ush* __restrict__ Wkh, const ush* __restrict__ Wkl,
    const ush* __restrict__ Wvh, const ush* __restrict__ Wvl,
    const float* __restrict__ bq, const float* __restrict__ bk,
    const float* __restrict__ bv,
    ush* __restrict__ Qh, ush* __restrict__ Ql,
    ush* __restrict__ Kh, ush* __restrict__ Kl, ush* __restrict__ Vt)
{
  constexpr int LDT = 40;
  __shared__ ush As[128*LDT], Bhs[128*LDT], Bls[128*LDT];

  const int z = blockIdx.z;
  const float* A  = (z==0)?Aq:(z==1)?Ak:Av;
  const ush* Bh   = (z==0)?Wqh:(z==1)?Wkh:Wvh;
  const ush* Bl   = (z==0)?Wql:(z==1)?Wkl:Wvl;
  const float* bias = (z==0)?bq:(z==1)?bk:bv;

  const int tid = threadIdx.x;
  const int lane = tid & 63, w = tid >> 6;
  const int c = lane & 15, g = lane >> 4;
  const int wr = w >> 1, wc = w & 1;
  const int m0 = blockIdx.y * 128, n0 = blockIdx.x * 128;

  f32x4 acc[4][4];
  #pragma unroll
  for (int i = 0; i < 4; ++i)
    #pragma unroll
    for (int j = 0; j < 4; ++j) acc[i][j] = (f32x4){0.f,0.f,0.f,0.f};

  const int sr = tid >> 1;
  const int sk = (tid & 1) * 16;

  float4 ar[4]; uint4 bhr[2], blr[2];
  #define ISSUE_PROJ(KT) do{ \
    const float* ap = A + (size_t)(m0 + sr)*DM + (KT) + sk; \
    ar[0] = *(const float4*)(ap);      ar[1] = *(const float4*)(ap + 4); \
    ar[2] = *(const float4*)(ap + 8);  ar[3] = *(const float4*)(ap + 12); \
    const ush* bp  = Bh + (size_t)(n0 + sr)*DM + (KT) + sk; \
    const ush* blp = Bl + (size_t)(n0 + sr)*DM + (KT) + sk; \
    bhr[0] = *(const uint4*)(bp);  bhr[1] = *(const uint4*)(bp + 8); \
    blr[0] = *(const uint4*)(blp); blr[1] = *(const uint4*)(blp + 8); \
  }while(0)

  ISSUE_PROJ(0);
  for (int kt = 0; kt < DM; kt += 32){
    {
      const float* av = (const float*)ar;
      unsigned int hu[8];
      #pragma unroll
      for (int p = 0; p < 8; ++p) hu[p] = pk2(av[2*p], av[2*p+1]);
      *(uint4*)&As[sr*LDT + sk]      = *(const uint4*)&hu[0];
      *(uint4*)&As[sr*LDT + sk + 8]  = *(const uint4*)&hu[4];
      *(uint4*)&Bhs[sr*LDT + sk]     = bhr[0];
      *(uint4*)&Bhs[sr*LDT + sk + 8] = bhr[1];
      *(uint4*)&Bls[sr*LDT + sk]     = blr[0];
      *(uint4*)&Bls[sr*LDT + sk + 8] = blr[1];
    }
    __syncthreads();
    if (kt + 32 < DM) ISSUE_PROJ(kt + 32);

    bf8_t a_h[4];
    #pragma unroll
    for (int fm = 0; fm < 4; ++fm)
      a_h[fm] = *(const bf8_t*)&As[(64*wr + 16*fm + c)*LDT + 8*g];
    #pragma unroll
    for (int fn = 0; fn < 4; ++fn){
      bf8_t b_h = *(const bf8_t*)&Bhs[(64*wc + 16*fn + c)*LDT + 8*g];
      #pragma unroll
      for (int fm = 0; fm < 4; ++fm)
        acc[fm][fn] = MFMA16(a_h[fm], b_h, acc[fm][fn]);
      bf8_t b_l = *(const bf8_t*)&Bls[(64*wc + 16*fn + c)*LDT + 8*g];
      #pragma unroll
      for (int fm = 0; fm < 4; ++fm)
        acc[fm][fn] = MFMA16(a_h[fm], b_l, acc[fm][fn]);
    }
    __syncthreads();
  }
  #undef ISSUE_PROJ

  // epilogue (C/D: col = lane&15, row = 4*(lane>>4)+reg)
  #pragma unroll
  for (int fm = 0; fm < 4; ++fm){
    #pragma unroll
    for (int fn = 0; fn < 4; ++fn){
      const int col = n0 + 64*wc + 16*fn + c;
      const float bb = bias[col];
      const int row0 = m0 + 64*wr + 16*fm + 4*g;
      const int hd = col >> 6, d = col & 63;
      if (z < 2){
        ush* oh = (z==0) ? Qh : Kh;
        ush* ol = (z==0) ? Ql : Kl;
        #pragma unroll
        for (int r = 0; r < 4; ++r){
          const int row = row0 + r;
          const int b = row >> 10, s = row & 1023;
          const size_t a = ((size_t)(b*NH + hd)*SS + s)*DKH + d;
          float vv = acc[fm][fn][r] + bb;
          ush hh = f2bf(vv);
          oh[a] = hh;
          ol[a] = f2bf(vv - bf2f(hh));
        }
      } else {
        const int b = row0 >> 10, s = row0 & 1023;
        const size_t a = ((size_t)(b*NH + hd)*DKH + d)*SS + s;
        uint2 pk;
        pk.x = pk2(acc[fm][fn][0] + bb, acc[fm][fn][1] + bb);
        pk.y = pk2(acc[fm][fn][2] + bb, acc[fm][fn][3] + bb);
        *(uint2*)&Vt[a] = pk;
      }
    }
  }
}

// ---- output projection: C = A(bf16) @ Wo^T + bo, 128x64 tile, reg-prefetch
__global__ __launch_bounds__(256) void gemm_out(
    const ush* __restrict__ Abf, const ush* __restrict__ Bth,
    const float* __restrict__ bias, float* __restrict__ outf)
{
  constexpr int LDT = 40;
  __shared__ ush As[128*LDT], Bs[64*LDT];

  const int tid = threadIdx.x;
  const int lane = tid & 63, w = tid >> 6;
  const int c = lane & 15, g = lane >> 4;
  const int wr = w >> 1, wc = w & 1;
  const int m0 = blockIdx.y * 128, n0 = blockIdx.x * 64;

  f32x4 acc[4][2];
  #pragma unroll
  for (int i = 0; i < 4; ++i){ acc[i][0] = (f32x4){0,0,0,0}; acc[i][1] = (f32x4){0,0,0,0}; }

  const int sr = tid >> 1, sk = (tid & 1) * 16;     // A staging
  const int br = tid >> 2, bk2 = (tid & 3) * 8;     // B staging

  uint4 ar0, ar1, brr;
  #define ISSUE_OUT(KT) do{ \
    const ush* ap = Abf + (size_t)(m0 + sr)*DM + (KT) + sk; \
    ar0 = *(const uint4*)(ap); ar1 = *(const uint4*)(ap + 8); \
    brr = *(const uint4*)(Bth + (size_t)(n0 + br)*DM + (KT) + bk2); \
  }while(0)

  ISSUE_OUT(0);
  for (int kt = 0; kt < DM; kt += 32){
    *(uint4*)&As[sr*LDT + sk]     = ar0;
    *(uint4*)&As[sr*LDT + sk + 8] = ar1;
    *(uint4*)&Bs[br*LDT + bk2]    = brr;
    __syncthreads();
    if (kt + 32 < DM) ISSUE_OUT(kt + 32);

    bf8_t a_h[4];
    #pragma unroll
    for (int fm = 0; fm < 4; ++fm)
      a_h[fm] = *(const bf8_t*)&As[(64*wr + 16*fm + c)*LDT + 8*g];
    #pragma unroll
    for (int fn = 0; fn < 2; ++fn){
      bf8_t b_h = *(const bf8_t*)&Bs[(32*wc + 16*fn + c)*LDT + 8*g];
      #pragma unroll
      for (int fm = 0; fm < 4; ++fm)
        acc[fm][fn] = MFMA16(a_h[fm], b_h, acc[fm][fn]);
    }
    __syncthreads();
  }
  #undef ISSUE_OUT

  #pragma unroll
  for (int fm = 0; fm < 4; ++fm){
    #pragma unroll
    for (int fn = 0; fn < 2; ++fn){
      const int col = n0 + 32*wc + 16*fn + c;
      const float bb = bias[col];
      const int row0 = m0 + 64*wr + 16*fm + 4*g;
      #pragma unroll
      for (int r = 0; r < 4; ++r)
        outf[(size_t)(row0 + r)*DM + col] = acc[fm][fn][r] + bb;
    }
  }
}

// ---- Stats pass (swapped QK^T, swizzled LDS, reg-prefetch, no max-subtraction)
__global__ __launch_bounds__(256) void attn_stats_mfma(
    const ush* __restrict__ Qh, const ush* __restrict__ Ql,
    const ush* __restrict__ Kh, float* __restrict__ stats)
{
  __shared__ ush Khs[64*64];
  __shared__ float red[4][3];
  const int tid = threadIdx.x, lane = tid & 63, w = tid >> 6;
  const int c = lane & 15, g = lane >> 4;
  const int bh = blockIdx.y, q0 = blockIdx.x * 64;

  bf8_t qh[2], ql[2];
  {
    const size_t qoff = ((size_t)bh*SS + q0 + 16*w + c)*DKH + 8*g;
    qh[0] = *(const bf8_t*)(Qh + qoff);  qh[1] = *(const bf8_t*)(Qh + qoff + 32);
    ql[0] = *(const bf8_t*)(Ql + qoff);  ql[1] = *(const bf8_t*)(Ql + qoff + 32);
  }

  float ssum = 0.f, rmax = -1e30f, lsum = 0.f, l2sum = 0.f;
  const int rr0 = tid >> 3, ci = tid & 7;

  uint4 kr[2];
  #define ISSUE_ST(KC) do{ \
    kr[0] = *(const uint4*)(Kh + ((size_t)bh*SS + (KC)*64 + rr0)*DKH + ci*8); \
    kr[1] = *(const uint4*)(Kh + ((size_t)bh*SS + (KC)*64 + rr0 + 32)*DKH + ci*8); \
  }while(0)

  ISSUE_ST(0);
  for (int kc = 0; kc < 16; ++kc){
    *(uint4*)&Khs[swz8(rr0,      ci)] = kr[0];
    *(uint4*)&Khs[swz8(rr0 + 32, ci)] = kr[1];
    __syncthreads();
    if (kc < 15) ISSUE_ST(kc + 1);

    f32x4 sa[4];
    #pragma unroll
    for (int fn = 0; fn < 4; ++fn) sa[fn] = (f32x4){0.f,0.f,0.f,0.f};
    __builtin_amdgcn_s_setprio(1);
    #pragma unroll
    for (int fn = 0; fn < 4; ++fn){
      #pragma unroll
      for (int ds = 0; ds < 2; ++ds){
        bf8_t ah = *(const bf8_t*)&Khs[swz8(16*fn + c, g + 4*ds)];
        sa[fn] = MFMA16(ah, qh[ds], sa[fn]);
        sa[fn] = MFMA16(ah, ql[ds], sa[fn]);
      }
    }
    __builtin_amdgcn_s_setprio(0);
    #pragma unroll
    for (int fn = 0; fn < 4; ++fn){
      #pragma unroll
      for (int r = 0; r < 4; ++r){
        float s = sa[fn][r] * 0.125f;
        s = fminf(fmaxf(s, -50.f), 50.f);
        ssum += s;
        rmax = fmaxf(rmax, s);
        float e = exp2f(s * 0.7213475204f);    // exp(s/2); clip keeps fp32 safe
        lsum += e;
        l2sum = fmaf(e, e, l2sum);
      }
    }
    __syncthreads();
  }
  #undef ISSUE_ST

  rmax  = fmaxf(rmax, __shfl_xor(rmax, 16, 64));
  rmax  = fmaxf(rmax, __shfl_xor(rmax, 32, 64));
  lsum  += __shfl_xor(lsum, 16, 64);   lsum  += __shfl_xor(lsum, 32, 64);
  l2sum += __shfl_xor(l2sum, 16, 64);  l2sum += __shfl_xor(l2sum, 32, 64);
  float varc = (l2sum/(lsum*lsum) - (1.0f/1024.f)) * (1.0f/1023.f);
  float a0 = ssum, a1 = rmax * 0.25f, a2 = varc * 0.25f;
  #pragma unroll
  for (int off = 1; off < 64; off <<= 1){
    a0 += __shfl_xor(a0, off, 64);
    a1 += __shfl_xor(a1, off, 64);
    a2 += __shfl_xor(a2, off, 64);
  }
  if (lane == 0){ red[w][0] = a0; red[w][1] = a1; red[w][2] = a2; }
  __syncthreads();
  if (tid == 0){
    atomicAdd(&stats[bh*4+0], red[0][0]+red[1][0]+red[2][0]+red[3][0]);
    atomicAdd(&stats[bh*4+1], red[0][1]+red[1][1]+red[2][1]+red[3][1]);
    atomicAdd(&stats[bh*4+2], red[0][2]+red[1][2]+red[2][2]+red[3][2]);
  }
}

__global__ void time_mlp(const float* __restrict__ stats,
    const float* __restrict__ Wt1, const float* __restrict__ bt1,
    const float* __restrict__ Wt2, const float* __restrict__ bt2,
    float* __restrict__ tws)
{
  int bh = threadIdx.x;
  if (bh >= NBH) return;
  float mean = stats[bh*4+0] * (1.f/(1024.f*1024.f));
  float mx   = stats[bh*4+1] * (1.f/1024.f);
  float ent  = stats[bh*4+2] * (1.f/1024.f);
  mean = fminf(fmaxf(mean, -10.f), 10.f);
  mx   = fminf(fmaxf(mx,   -10.f), 10.f);
  ent  = fminf(fmaxf(ent,    0.f),  1.f);
  float raw = bt2[0];
  #pragma unroll
  for (int j = 0; j < 16; ++j){
    float h = tanhf(mean*Wt1[j] + mx*Wt1[16+j] + ent*Wt1[32+j] + bt1[j]);
    raw += h * Wt2[j];
  }
  float sig = 1.f / (1.f + expf(-raw));
  float t = 0.01f + sig * 1.99f;
  t = fminf(fmaxf(t, 0.01f), 2.0f);
  t = fminf(t, 0.85f);
  tws[bh] = t;
}

// ---- Flash pass (swapped QK^T, exp2 domain, defer-max, swizzled LDS, prefetch)
__global__ __launch_bounds__(256) void attn_flash_mfma(
    const ush* __restrict__ Qh, const ush* __restrict__ Ql,
    const ush* __restrict__ Kh, const ush* __restrict__ Kl,
    const ush* __restrict__ Vt, const float* __restrict__ tws,
    ush* __restrict__ aout)
{
  __shared__ ush Khs[64*64], Kls[64*64], Vts[64*64], Ps[64*64];
  __shared__ float Ls[4][16];
  const int tid = threadIdx.x, lane = tid & 63, w = tid >> 6;
  const int c = lane & 15, g = lane >> 4;
  const int bh = blockIdx.y, q0 = blockIdx.x * 64;
  const float tsc2 = (0.5f / tws[bh]) * 1.44269504f;   // exp2 domain

  bf8_t qh[2], ql[2];
  {
    const size_t qoff = ((size_t)bh*SS + q0 + 16*w + c)*DKH + 8*g;
    qh[0] = *(const bf8_t*)(Qh + qoff);  qh[1] = *(const bf8_t*)(Qh + qoff + 32);
    ql[0] = *(const bf8_t*)(Ql + qoff);  ql[1] = *(const bf8_t*)(Ql + qoff + 32);
  }

  f32x4 o[4];
  #pragma unroll
  for (int i = 0; i < 4; ++i) o[i] = (f32x4){0.f,0.f,0.f,0.f};
  float m = -INFINITY, l = 0.f;

  const int rr0 = tid >> 3, ci = tid & 7;

  uint4 kr[2], klr[2], vr[2];
  #define ISSUE_FL(KC) do{ \
    const size_t gk0 = ((size_t)bh*SS + (KC)*64 + rr0)*DKH + ci*8; \
    const size_t gk1 = ((size_t)bh*SS + (KC)*64 + rr0 + 32)*DKH + ci*8; \
    kr[0]  = *(const uint4*)(Kh + gk0);  kr[1]  = *(const uint4*)(Kh + gk1); \
    klr[0] = *(const uint4*)(Kl + gk0);  klr[1] = *(const uint4*)(Kl + gk1); \
    vr[0] = *(const uint4*)(Vt + ((size_t)bh*DKH + rr0)*SS + (KC)*64 + ci*8); \
    vr[1] = *(const uint4*)(Vt + ((size_t)bh*DKH + rr0 + 32)*SS + (KC)*64 + ci*8); \
  }while(0)

  ISSUE_FL(0);
  for (int kc = 0; kc < 16; ++kc){
    *(uint4*)&Khs[swz8(rr0,      ci)] = kr[0];
    *(uint4*)&Khs[swz8(rr0 + 32, ci)] = kr[1];
    *(uint4*)&Kls[swz8(rr0,      ci)] = klr[0];
    *(uint4*)&Kls[swz8(rr0 + 32, ci)] = klr[1];
    *(uint4*)&Vts[swz8(rr0,      ci)] = vr[0];
    *(uint4*)&Vts[swz8(rr0 + 32, ci)] = vr[1];
    __syncthreads();
    if (kc < 15) ISSUE_FL(kc + 1);

    f32x4 sa[4];
    #pragma unroll
    for (int fn = 0; fn < 4; ++fn) sa[fn] = (f32x4){0.f,0.f,0.f,0.f};
    __builtin_amdgcn_s_setprio(1);
    #pragma unroll
    for (int fn = 0; fn < 4; ++fn){
      #pragma unroll
      for (int ds = 0; ds < 2; ++ds){
        bf8_t ah = *(const bf8_t*)&Khs[swz8(16*fn + c, g + 4*ds)];
        bf8_t al = *(const bf8_t*)&Kls[swz8(16*fn + c, g + 4*ds)];
        sa[fn] = MFMA16(ah, qh[ds], sa[fn]);   // 3-term split
        sa[fn] = MFMA16(al, qh[ds], sa[fn]);
        sa[fn] = MFMA16(ah, ql[ds], sa[fn]);
      }
    }
    __builtin_amdgcn_s_setprio(0);

    // lane-local softmax for q-row (q0+16w+c), kv split over g
    float x[4][4];
    float pmax = -1e30f;
    #pragma unroll
    for (int fn = 0; fn < 4; ++fn)
      #pragma unroll
      for (int r = 0; r < 4; ++r){
        x[fn][r] = sa[fn][r] * tsc2;
        pmax = fmaxf(pmax, x[fn][r]);
      }
    pmax = fmaxf(pmax, __shfl_xor(pmax, 16, 64));
    pmax = fmaxf(pmax, __shfl_xor(pmax, 32, 64));

    if (!__all(pmax <= m + 30.f)){       // defer-max: fires ~once (kc=0)
      float mn = fmaxf(m, pmax);
      float sc = exp2f(m - mn);
      m = mn;
      l *= sc;
      Ls[w][c] = sc;
      #pragma unroll
      for (int r = 0; r < 4; ++r){
        float so = Ls[w][4*g + r];
        #pragma unroll
        for (int fn = 0; fn < 4; ++fn) o[fn][r] *= so;
      }
    }

    float lsum = 0.f;
    #pragma unroll
    for (int fn = 0; fn < 4; ++fn){
      float e0 = exp2f(x[fn][0] - m);
      float e1 = exp2f(x[fn][1] - m);
      float e2 = exp2f(x[fn][2] - m);
      float e3 = exp2f(x[fn][3] - m);
      lsum += (e0 + e1) + (e2 + e3);
      uint2 pk;
      pk.x = pk2(e0, e1);
      pk.y = pk2(e2, e3);
      const int q4 = 4*fn + g;           // 4-ush col index
      const int addr = (16*w + c)*64 + ((((q4 >> 1) ^ (c & 7)) << 3)) + (q4 & 1)*4;
      *(uint2*)&Ps[addr] = pk;
    }
    lsum += __shfl_xor(lsum, 16, 64);
    lsum += __shfl_xor(lsum, 32, 64);
    l += lsum;

    // PV: A = P rows (wave-local), B = V^T tile
    __builtin_amdgcn_s_setprio(1);
    #pragma unroll
    for (int kvs = 0; kvs < 2; ++kvs){
      bf8_t pa = *(const bf8_t*)&Ps[swz8(16*w + c, g + 4*kvs)];
      #pragma unroll
      for (int fn = 0; fn < 4; ++fn){
        bf8_t vb = *(const bf8_t*)&Vts[swz8(16*fn + c, g + 4*kvs)];
        o[fn] = MFMA16(pa, vb, o[fn]);
      }
    }
    __builtin_amdgcn_s_setprio(0);
    __syncthreads();
  }
  #undef ISSUE_FL

  Ls[w][c] = l;
  const int b = bh >> 4, hd = bh & 15;
  #pragma unroll
  for (int r = 0; r < 4; ++r){
    float linv = 1.f / Ls[w][4*g + r];
    const int q = q0 + 16*w + 4*g + r;
    #pragma unroll
    for (int fn = 0; fn < 4; ++fn)
      aout[((size_t)(b*SS + q))*DM + hd*DKH + 16*fn + c] = f2bf(o[fn][r] * linv);
  }
}

extern "C" void kernel_launch(void* const* d_in, const int* in_sizes, int n_in,
                              void* d_out, int out_size, void* d_ws, size_t ws_size,
                              hipStream_t stream)
{
  const float* query = (const float*)d_in[0];
  const float* key   = (const float*)d_in[1];
  const float* value = (const float*)d_in[2];
  const float* Wq = (const float*)d_in[3];
  const float* bq = (const float*)d_in[4];
  const float* Wk = (const float*)d_in[5];
  const float* bk = (const float*)d_in[6];
  const float* Wv = (const float*)d_in[7];
  const float* bv = (const float*)d_in[8];
  const float* Wo = (const float*)d_in[9];
  const float* bo = (const float*)d_in[10];
  const float* Wt1 = (const float*)d_in[11];
  const float* bt1 = (const float*)d_in[12];
  const float* Wt2 = (const float*)d_in[13];
  const float* bt2 = (const float*)d_in[14];

  ush* ws16 = (ush*)d_ws;
  const size_t E = (size_t)NB*SS*DM;
  const size_t WE = (size_t)DM*DM;
  ush* Qhb = ws16;
  ush* Qlb = Qhb + E;
  ush* Khb = Qlb + E;
  ush* Klb = Khb + E;
  ush* Vtb = Klb + E;
  ush* Aob = Vtb + E;
  ush* Wqh = Aob + E;
  ush* Wql = Wqh + WE;
  ush* Wkh = Wql + WE;
  ush* Wkl = Wkh + WE;
  ush* Wvh = Wkl + WE;
  ush* Wvl = Wvh + WE;
  ush* Woh = Wvl + WE;
  float* stats = (float*)(Woh + WE);
  float* tws   = stats + 4*NBH;

  hipMemsetAsync(stats, 0, 4*NBH*sizeof(float), stream);

  dim3 wb(32, 8), wg(32, 32, 4);
  wconv4<<<wg, wb, 0, stream>>>(Wq, Wk, Wv, Wo, Wqh, Wkh, Wvh, Woh, Wql, Wkl, Wvl);

  dim3 gp(DM/128, (NB*SS)/128, 3);         // (8, 32, 3) = 768 blocks
  proj_qkv<<<gp, 256, 0, stream>>>(query, key, value,
      Wqh, Wql, Wkh, Wkl, Wvh, Wvl, bq, bk, bv,
      Qhb, Qlb, Khb, Klb, Vtb);

  dim3 ga(SS/64, NBH);                     // (16, 64)
  attn_stats_mfma<<<ga, 256, 0, stream>>>(Qhb, Qlb, Khb, stats);
  time_mlp<<<1, 64, 0, stream>>>(stats, Wt1, bt1, Wt2, bt2, tws);
  attn_flash_mfma<<<ga, 256, 0, stream>>>(Qhb, Qlb, Khb, Klb, Vtb, tws, Aob);

  dim3 go(DM/64, (NB*SS)/128);             // (16, 32) = 512 blocks
  gemm_out<<<go, 256, 0, stream>>>(Aob, Woh, bo, (float*)d_out);
}

// Round 5
// 207.984 us; speedup vs baseline: 1.8342x; 1.8342x over previous
//
#include <hip/hip_runtime.h>
#include <hip/hip_bf16.h>
#include <math.h>

#define SS   1024
#define DM   1024
#define NH   16
#define DKH  64
#define NB   4
#define NBH  64

typedef unsigned short ush;
typedef unsigned int uint32;
typedef __attribute__((ext_vector_type(8))) short bf8_t;   // 8 bf16 = 4 VGPR
typedef __attribute__((ext_vector_type(4))) float f32x4;
#define MFMA16(a,b,c) __builtin_amdgcn_mfma_f32_16x16x32_bf16((a),(b),(c),0,0,0)

__device__ __forceinline__ ush f2bf(float x){ return __bfloat16_as_ushort(__float2bfloat16(x)); }
__device__ __forceinline__ float bf2f(ush h){ return __bfloat162float(__ushort_as_bfloat16(h)); }
__device__ __forceinline__ uint32 pk2(float a, float b){
  return (uint32)f2bf(a) | ((uint32)f2bf(b) << 16);
}
// pack value as (lo16<<16)|hi16
__device__ __forceinline__ uint32 pkhl(float v){
  ush h = f2bf(v);
  return (uint32)h | ((uint32)f2bf(v - bf2f(h)) << 16);
}
// extract hi/lo bf16 pairs from two interleaved uints (ulo = smaller d)
__device__ __forceinline__ uint32 prmh(uint32 uhi, uint32 ulo){
  return __builtin_amdgcn_perm(uhi, ulo, 0x05040100u);
}
__device__ __forceinline__ uint32 prml(uint32 uhi, uint32 ulo){
  return __builtin_amdgcn_perm(uhi, ulo, 0x07060302u);
}
// [64][64]-ush tile, XOR swizzle on 16B chunks
__device__ __forceinline__ int swz8(int row, int chunk){
  return row*64 + (((chunk) ^ (row & 7)) << 3);
}
union U4B8 { uint4 u; bf8_t b; };

// ---- x fp32 -> bf16 (hi only)
__global__ __launch_bounds__(256) void xconv(
    const float* __restrict__ q, const float* __restrict__ k, const float* __restrict__ v,
    ush* __restrict__ xq, ush* __restrict__ xk, ush* __restrict__ xv)
{
  const float* src = (blockIdx.y==0)?q:(blockIdx.y==1)?k:v;
  ush* dst = (blockIdx.y==0)?xq:(blockIdx.y==1)?xk:xv;
  const size_t i = ((size_t)blockIdx.x*256 + threadIdx.x)*8;
  float4 a = *(const float4*)&src[i];
  float4 b = *(const float4*)&src[i+4];
  uint4 o;
  o.x = pk2(a.x, a.y); o.y = pk2(a.z, a.w);
  o.z = pk2(b.x, b.y); o.w = pk2(b.z, b.w);
  *(uint4*)&dst[i] = o;
}

// ---- weight convert: W (K x N) fp32 -> Wt (N x K) bf16 hi (+lo for z<3)
__global__ void wconv4(const float* __restrict__ W0, const float* __restrict__ W1,
                       const float* __restrict__ W2, const float* __restrict__ W3,
                       ush* __restrict__ H0, ush* __restrict__ H1,
                       ush* __restrict__ H2, ush* __restrict__ H3,
                       ush* __restrict__ L0, ush* __restrict__ L1,
                       ush* __restrict__ L2)
{
  __shared__ float T[32][33];
  const int tx = threadIdx.x, ty = threadIdx.y;    // (32,8)
  const int z = blockIdx.z;
  const float* W = (z==0)?W0:(z==1)?W1:(z==2)?W2:W3;
  ush* H = (z==0)?H0:(z==1)?H1:(z==2)?H2:H3;
  ush* L = (z==0)?L0:(z==1)?L1:(z==2)?L2:nullptr;
  const int k0 = blockIdx.y*32, n0 = blockIdx.x*32;
  #pragma unroll
  for (int i = 0; i < 4; ++i){
    int r = ty + 8*i;
    T[r][tx] = W[(size_t)(k0 + r)*DM + n0 + tx];
  }
  __syncthreads();
  #pragma unroll
  for (int i = 0; i < 4; ++i){
    int r = ty + 8*i;              // n-local
    float v = T[tx][r];
    ush hh = f2bf(v);
    H[(size_t)(n0 + r)*DM + k0 + tx] = hh;
    if (z < 3) L[(size_t)(n0 + r)*DM + k0 + tx] = f2bf(v - bf2f(hh));
  }
}

// ---- fused Q/K/V projection, XCD-chunked swizzle, bf16 A, 2-term split-B.
// Q/K out: interleaved (hi|lo) uint32 at (b*16+h, s, dk); V out: bf16 (b*16+h, dk, s)
__global__ __launch_bounds__(256) void proj_qkv(
    const ush* __restrict__ xq, const ush* __restrict__ xk, const ush* __restrict__ xv,
    const ush* __restrict__ Wqh, const ush* __restrict__ Wql,
    const ush* __restrict__ Wkh, const ush* __restrict__ Wkl,
    const ush* __restrict__ Wvh, const ush* __restrict__ Wvl,
    const float* __restrict__ bq, const float* __restrict__ bk,
    const float* __restrict__ bv,
    uint32* __restrict__ Qi, uint32* __restrict__ Ki, ush* __restrict__ Vt)
{
  constexpr int LDT = 40;
  __shared__ ush SMEM[16896];                 // staging 3*5120; V-epilogue 4*4224
  ush* As  = SMEM;
  ush* Bhs = SMEM + 5120;
  ush* Bls = SMEM + 10240;

  const int fid = blockIdx.x;
  const int glob = (fid & 7)*96 + (fid >> 3);  // XCD-contiguous chunks of 96
  const int z = glob >> 8, rem = glob & 255;
  const int m0 = (rem >> 3) * 128, n0 = (rem & 7) * 128;

  const ush* A  = (z==0) ? xq  : (z==1) ? xk  : xv;
  const ush* Bh = (z==0) ? Wqh : (z==1) ? Wkh : Wvh;
  const ush* Bl = (z==0) ? Wql : (z==1) ? Wkl : Wvl;
  const float* bias = (z==0) ? bq : (z==1) ? bk : bv;

  const int tid = threadIdx.x;
  const int lane = tid & 63, w = tid >> 6;
  const int c = lane & 15, g = lane >> 4;
  const int wr = w >> 1, wc = w & 1;

  f32x4 acc[4][4];
  #pragma unroll
  for (int i = 0; i < 4; ++i)
    #pragma unroll
    for (int j = 0; j < 4; ++j) acc[i][j] = (f32x4){0.f,0.f,0.f,0.f};

  const int sr = tid >> 1;
  const int sk = (tid & 1) * 16;

  uint4 ar0, ar1, bh0, bh1, bl0, bl1;
  #define ISSUE_PROJ(KT) do{ \
    const ush* ap = A + (size_t)(m0 + sr)*DM + (KT) + sk; \
    ar0 = *(const uint4*)(ap);  ar1 = *(const uint4*)(ap + 8); \
    const ush* bp  = Bh + (size_t)(n0 + sr)*DM + (KT) + sk; \
    const ush* blp = Bl + (size_t)(n0 + sr)*DM + (KT) + sk; \
    bh0 = *(const uint4*)(bp);  bh1 = *(const uint4*)(bp + 8); \
    bl0 = *(const uint4*)(blp); bl1 = *(const uint4*)(blp + 8); \
  }while(0)

  ISSUE_PROJ(0);
  for (int kt = 0; kt < DM; kt += 32){
    *(uint4*)&As[sr*LDT + sk]      = ar0;
    *(uint4*)&As[sr*LDT + sk + 8]  = ar1;
    *(uint4*)&Bhs[sr*LDT + sk]     = bh0;
    *(uint4*)&Bhs[sr*LDT + sk + 8] = bh1;
    *(uint4*)&Bls[sr*LDT + sk]     = bl0;
    *(uint4*)&Bls[sr*LDT + sk + 8] = bl1;
    __syncthreads();
    if (kt + 32 < DM) ISSUE_PROJ(kt + 32);

    bf8_t a_h[4];
    #pragma unroll
    for (int fm = 0; fm < 4; ++fm)
      a_h[fm] = *(const bf8_t*)&As[(64*wr + 16*fm + c)*LDT + 8*g];
    #pragma unroll
    for (int fn = 0; fn < 4; ++fn){
      bf8_t b_h = *(const bf8_t*)&Bhs[(64*wc + 16*fn + c)*LDT + 8*g];
      #pragma unroll
      for (int fm = 0; fm < 4; ++fm)
        acc[fm][fn] = MFMA16(a_h[fm], b_h, acc[fm][fn]);
      bf8_t b_l = *(const bf8_t*)&Bls[(64*wc + 16*fn + c)*LDT + 8*g];
      #pragma unroll
      for (int fm = 0; fm < 4; ++fm)
        acc[fm][fn] = MFMA16(a_h[fm], b_l, acc[fm][fn]);
    }
    __syncthreads();
  }
  #undef ISSUE_PROJ

  if (z < 2){
    uint32* O = (z==0) ? Qi : Ki;
    #pragma unroll
    for (int fm = 0; fm < 4; ++fm){
      #pragma unroll
      for (int fn = 0; fn < 4; ++fn){
        const int col = n0 + 64*wc + 16*fn + c;
        const float bb = bias[col];
        const int row0 = m0 + 64*wr + 16*fm + 4*g;
        const int hd = col >> 6, d = col & 63;
        #pragma unroll
        for (int r = 0; r < 4; ++r){
          const int row = row0 + r;
          const int b = row >> 10, s = row & 1023;
          O[((size_t)(b*NH + hd)*SS + s)*DKH + d] = pkhl(acc[fm][fn][r] + bb);
        }
      }
    }
  } else {
    // V: transpose wave's 64(s) x 64(d) sub-tile through LDS -> coalesced (d,s) writes
    __syncthreads();                       // staging reads complete before reuse
    ush* Vep = SMEM + w*4224;              // 64 rows(d) x 66 cols(s)
    #pragma unroll
    for (int fm = 0; fm < 4; ++fm){
      #pragma unroll
      for (int fn = 0; fn < 4; ++fn){
        const float bb = bias[n0 + 64*wc + 16*fn + c];
        #pragma unroll
        for (int r = 0; r < 4; ++r)
          Vep[(16*fn + c)*66 + 16*fm + 4*g + r] = f2bf(acc[fm][fn][r] + bb);
      }
    }
    const int b = m0 >> 10;
    const int s0 = (m0 & 1023) + 64*wr;
    const int hd = (n0 >> 6) + wc;
    const size_t vbase = ((size_t)(b*NH + hd))*DKH*SS;
    #pragma unroll
    for (int it = 0; it < 8; ++it){
      const int dr = 8*it + (lane >> 3);
      const int sc = (lane & 7)*8;
      uint4 vv = *(const uint4*)&Vep[dr*66 + sc];
      *(uint4*)&Vt[vbase + (size_t)dr*SS + s0 + sc] = vv;
    }
  }
}

// ---- output projection: C = A(bf16) @ Wo^T + bo, 128x64 tile, swizzle, prefetch
__global__ __launch_bounds__(256) void gemm_out(
    const ush* __restrict__ Abf, const ush* __restrict__ Bth,
    const float* __restrict__ bias, float* __restrict__ outf)
{
  constexpr int LDT = 40;
  __shared__ ush As[128*LDT], Bs[64*LDT];

  const int fid = blockIdx.x;
  const int glob = (fid & 7)*64 + (fid >> 3);
  const int m0 = (glob >> 4)*128, n0 = (glob & 15)*64;

  const int tid = threadIdx.x;
  const int lane = tid & 63, w = tid >> 6;
  const int c = lane & 15, g = lane >> 4;
  const int wr = w >> 1, wc = w & 1;

  f32x4 acc[4][2];
  #pragma unroll
  for (int i = 0; i < 4; ++i){ acc[i][0] = (f32x4){0,0,0,0}; acc[i][1] = (f32x4){0,0,0,0}; }

  const int sr = tid >> 1, sk = (tid & 1) * 16;
  const int br = tid >> 2, bk2 = (tid & 3) * 8;

  uint4 ar0, ar1, brr;
  #define ISSUE_OUT(KT) do{ \
    const ush* ap = Abf + (size_t)(m0 + sr)*DM + (KT) + sk; \
    ar0 = *(const uint4*)(ap); ar1 = *(const uint4*)(ap + 8); \
    brr = *(const uint4*)(Bth + (size_t)(n0 + br)*DM + (KT) + bk2); \
  }while(0)

  ISSUE_OUT(0);
  for (int kt = 0; kt < DM; kt += 32){
    *(uint4*)&As[sr*LDT + sk]     = ar0;
    *(uint4*)&As[sr*LDT + sk + 8] = ar1;
    *(uint4*)&Bs[br*LDT + bk2]    = brr;
    __syncthreads();
    if (kt + 32 < DM) ISSUE_OUT(kt + 32);

    bf8_t a_h[4];
    #pragma unroll
    for (int fm = 0; fm < 4; ++fm)
      a_h[fm] = *(const bf8_t*)&As[(64*wr + 16*fm + c)*LDT + 8*g];
    #pragma unroll
    for (int fn = 0; fn < 2; ++fn){
      bf8_t b_h = *(const bf8_t*)&Bs[(32*wc + 16*fn + c)*LDT + 8*g];
      #pragma unroll
      for (int fm = 0; fm < 4; ++fm)
        acc[fm][fn] = MFMA16(a_h[fm], b_h, acc[fm][fn]);
    }
    __syncthreads();
  }
  #undef ISSUE_OUT

  #pragma unroll
  for (int fm = 0; fm < 4; ++fm){
    #pragma unroll
    for (int fn = 0; fn < 2; ++fn){
      const int col = n0 + 32*wc + 16*fn + c;
      const float bb = bias[col];
      const int row0 = m0 + 64*wr + 16*fm + 4*g;
      #pragma unroll
      for (int r = 0; r < 4; ++r)
        outf[(size_t)(row0 + r)*DM + col] = acc[fm][fn][r] + bb;
    }
  }
}

// ---- Stats pass (swapped QK^T, swizzled LDS, prefetch, no max-subtraction)
__global__ __launch_bounds__(256) void attn_stats_mfma(
    const uint32* __restrict__ Qi, const uint32* __restrict__ Ki,
    float* __restrict__ stats)
{
  __shared__ ush Khs[64*64];
  __shared__ float red[4][3];
  const int tid = threadIdx.x, lane = tid & 63, w = tid >> 6;
  const int c = lane & 15, g = lane >> 4;
  const int fid = blockIdx.x;
  const int glob = (fid & 7)*128 + (fid >> 3);
  const int bh = glob >> 4, q0 = (glob & 15)*64;

  bf8_t qh[2], ql[2];
  {
    const size_t qoff = ((size_t)bh*SS + q0 + 16*w + c)*DKH + 8*g;
    uint4 u0 = *(const uint4*)(Qi + qoff);
    uint4 u1 = *(const uint4*)(Qi + qoff + 4);
    uint4 u2 = *(const uint4*)(Qi + qoff + 32);
    uint4 u3 = *(const uint4*)(Qi + qoff + 36);
    U4B8 t;
    t.u = (uint4){prmh(u0.y,u0.x), prmh(u0.w,u0.z), prmh(u1.y,u1.x), prmh(u1.w,u1.z)}; qh[0] = t.b;
    t.u = (uint4){prml(u0.y,u0.x), prml(u0.w,u0.z), prml(u1.y,u1.x), prml(u1.w,u1.z)}; ql[0] = t.b;
    t.u = (uint4){prmh(u2.y,u2.x), prmh(u2.w,u2.z), prmh(u3.y,u3.x), prmh(u3.w,u3.z)}; qh[1] = t.b;
    t.u = (uint4){prml(u2.y,u2.x), prml(u2.w,u2.z), prml(u3.y,u3.x), prml(u3.w,u3.z)}; ql[1] = t.b;
  }

  float ssum = 0.f, rmax = -1e30f, lsum = 0.f, l2sum = 0.f;
  const int srow = tid >> 2, sch = tid & 3;

  uint4 s0, s1, s2, s3;
  #define ISSUE_ST(KC) do{ \
    const uint32* kp = Ki + ((size_t)bh*SS + (KC)*64 + srow)*DKH; \
    s0 = *(const uint4*)(kp + sch*8);      s1 = *(const uint4*)(kp + sch*8 + 4); \
    s2 = *(const uint4*)(kp + (sch+4)*8);  s3 = *(const uint4*)(kp + (sch+4)*8 + 4); \
  }while(0)

  ISSUE_ST(0);
  for (int kc = 0; kc < 16; ++kc){
    {
      U4B8 t;
      t.u = (uint4){prmh(s0.y,s0.x), prmh(s0.w,s0.z), prmh(s1.y,s1.x), prmh(s1.w,s1.z)};
      *(uint4*)&Khs[swz8(srow, sch)] = t.u;
      t.u = (uint4){prmh(s2.y,s2.x), prmh(s2.w,s2.z), prmh(s3.y,s3.x), prmh(s3.w,s3.z)};
      *(uint4*)&Khs[swz8(srow, sch + 4)] = t.u;
    }
    __syncthreads();
    if (kc < 15) ISSUE_ST(kc + 1);

    f32x4 sa[4];
    #pragma unroll
    for (int fn = 0; fn < 4; ++fn) sa[fn] = (f32x4){0.f,0.f,0.f,0.f};
    __builtin_amdgcn_s_setprio(1);
    #pragma unroll
    for (int fn = 0; fn < 4; ++fn){
      #pragma unroll
      for (int ds = 0; ds < 2; ++ds){
        bf8_t ah = *(const bf8_t*)&Khs[swz8(16*fn + c, g + 4*ds)];
        sa[fn] = MFMA16(ah, qh[ds], sa[fn]);
        sa[fn] = MFMA16(ah, ql[ds], sa[fn]);
      }
    }
    __builtin_amdgcn_s_setprio(0);
    #pragma unroll
    for (int fn = 0; fn < 4; ++fn){
      #pragma unroll
      for (int r = 0; r < 4; ++r){
        float s = sa[fn][r] * 0.125f;
        s = fminf(fmaxf(s, -50.f), 50.f);
        ssum += s;
        rmax = fmaxf(rmax, s);
        float e = exp2f(s * 0.7213475204f);    // exp(s/2); clip keeps fp32 safe
        lsum += e;
        l2sum = fmaf(e, e, l2sum);
      }
    }
    __syncthreads();
  }
  #undef ISSUE_ST

  rmax  = fmaxf(rmax, __shfl_xor(rmax, 16, 64));
  rmax  = fmaxf(rmax, __shfl_xor(rmax, 32, 64));
  lsum  += __shfl_xor(lsum, 16, 64);   lsum  += __shfl_xor(lsum, 32, 64);
  l2sum += __shfl_xor(l2sum, 16, 64);  l2sum += __shfl_xor(l2sum, 32, 64);
  float varc = (l2sum/(lsum*lsum) - (1.0f/1024.f)) * (1.0f/1023.f);
  float a0 = ssum, a1 = rmax * 0.25f, a2 = varc * 0.25f;
  #pragma unroll
  for (int off = 1; off < 64; off <<= 1){
    a0 += __shfl_xor(a0, off, 64);
    a1 += __shfl_xor(a1, off, 64);
    a2 += __shfl_xor(a2, off, 64);
  }
  if (lane == 0){ red[w][0] = a0; red[w][1] = a1; red[w][2] = a2; }
  __syncthreads();
  if (tid == 0){
    atomicAdd(&stats[bh*4+0], red[0][0]+red[1][0]+red[2][0]+red[3][0]);
    atomicAdd(&stats[bh*4+1], red[0][1]+red[1][1]+red[2][1]+red[3][1]);
    atomicAdd(&stats[bh*4+2], red[0][2]+red[1][2]+red[2][2]+red[3][2]);
  }
}

__global__ void time_mlp(const float* __restrict__ stats,
    const float* __restrict__ Wt1, const float* __restrict__ bt1,
    const float* __restrict__ Wt2, const float* __restrict__ bt2,
    float* __restrict__ tws)
{
  int bh = threadIdx.x;
  if (bh >= NBH) return;
  float mean = stats[bh*4+0] * (1.f/(1024.f*1024.f));
  float mx   = stats[bh*4+1] * (1.f/1024.f);
  float ent  = stats[bh*4+2] * (1.f/1024.f);
  mean = fminf(fmaxf(mean, -10.f), 10.f);
  mx   = fminf(fmaxf(mx,   -10.f), 10.f);
  ent  = fminf(fmaxf(ent,    0.f),  1.f);
  float raw = bt2[0];
  #pragma unroll
  for (int j = 0; j < 16; ++j){
    float h = tanhf(mean*Wt1[j] + mx*Wt1[16+j] + ent*Wt1[32+j] + bt1[j]);
    raw += h * Wt2[j];
  }
  float sig = 1.f / (1.f + expf(-raw));
  float t = 0.01f + sig * 1.99f;
  t = fminf(fmaxf(t, 0.01f), 2.0f);
  t = fminf(t, 0.85f);
  tws[bh] = t;
}

// ---- Flash pass (swapped QK^T, exp2, defer-max, swizzled LDS, prefetch)
__global__ __launch_bounds__(256) void attn_flash_mfma(
    const uint32* __restrict__ Qi, const uint32* __restrict__ Ki,
    const ush* __restrict__ Vt, const float* __restrict__ tws,
    ush* __restrict__ aout)
{
  __shared__ ush Khs[64*64], Kls[64*64], Vts[64*64], Ps[64*64];
  __shared__ float Ls[4][16];
  const int tid = threadIdx.x, lane = tid & 63, w = tid >> 6;
  const int c = lane & 15, g = lane >> 4;
  const int fid = blockIdx.x;
  const int glob = (fid & 7)*128 + (fid >> 3);
  const int bh = glob >> 4, q0 = (glob & 15)*64;
  const float tsc2 = (0.5f / tws[bh]) * 1.44269504f;   // exp2 domain

  bf8_t qh[2], ql[2];
  {
    const size_t qoff = ((size_t)bh*SS + q0 + 16*w + c)*DKH + 8*g;
    uint4 u0 = *(const uint4*)(Qi + qoff);
    uint4 u1 = *(const uint4*)(Qi + qoff + 4);
    uint4 u2 = *(const uint4*)(Qi + qoff + 32);
    uint4 u3 = *(const uint4*)(Qi + qoff + 36);
    U4B8 t;
    t.u = (uint4){prmh(u0.y,u0.x), prmh(u0.w,u0.z), prmh(u1.y,u1.x), prmh(u1.w,u1.z)}; qh[0] = t.b;
    t.u = (uint4){prml(u0.y,u0.x), prml(u0.w,u0.z), prml(u1.y,u1.x), prml(u1.w,u1.z)}; ql[0] = t.b;
    t.u = (uint4){prmh(u2.y,u2.x), prmh(u2.w,u2.z), prmh(u3.y,u3.x), prmh(u3.w,u3.z)}; qh[1] = t.b;
    t.u = (uint4){prml(u2.y,u2.x), prml(u2.w,u2.z), prml(u3.y,u3.x), prml(u3.w,u3.z)}; ql[1] = t.b;
  }

  f32x4 o[4];
  #pragma unroll
  for (int i = 0; i < 4; ++i) o[i] = (f32x4){0.f,0.f,0.f,0.f};
  float m = -INFINITY, l = 0.f;

  const int rr0 = tid >> 3, ci = tid & 7;

  uint4 k0a, k0b, k1a, k1b, vr0, vr1;
  #define ISSUE_FL(KC) do{ \
    const uint32* kp0 = Ki + ((size_t)bh*SS + (KC)*64 + rr0)*DKH + ci*8; \
    const uint32* kp1 = kp0 + 32*DKH; \
    k0a = *(const uint4*)(kp0);  k0b = *(const uint4*)(kp0 + 4); \
    k1a = *(const uint4*)(kp1);  k1b = *(const uint4*)(kp1 + 4); \
    vr0 = *(const uint4*)(Vt + ((size_t)bh*DKH + rr0)*SS + (KC)*64 + ci*8); \
    vr1 = *(const uint4*)(Vt + ((size_t)bh*DKH + rr0 + 32)*SS + (KC)*64 + ci*8); \
  }while(0)

  ISSUE_FL(0);
  for (int kc = 0; kc < 16; ++kc){
    {
      U4B8 t;
      t.u = (uint4){prmh(k0a.y,k0a.x), prmh(k0a.w,k0a.z), prmh(k0b.y,k0b.x), prmh(k0b.w,k0b.z)};
      *(uint4*)&Khs[swz8(rr0, ci)] = t.u;
      t.u = (uint4){prml(k0a.y,k0a.x), prml(k0a.w,k0a.z), prml(k0b.y,k0b.x), prml(k0b.w,k0b.z)};
      *(uint4*)&Kls[swz8(rr0, ci)] = t.u;
      t.u = (uint4){prmh(k1a.y,k1a.x), prmh(k1a.w,k1a.z), prmh(k1b.y,k1b.x), prmh(k1b.w,k1b.z)};
      *(uint4*)&Khs[swz8(rr0 + 32, ci)] = t.u;
      t.u = (uint4){prml(k1a.y,k1a.x), prml(k1a.w,k1a.z), prml(k1b.y,k1b.x), prml(k1b.w,k1b.z)};
      *(uint4*)&Kls[swz8(rr0 + 32, ci)] = t.u;
      *(uint4*)&Vts[swz8(rr0,      ci)] = vr0;
      *(uint4*)&Vts[swz8(rr0 + 32, ci)] = vr1;
    }
    __syncthreads();
    if (kc < 15) ISSUE_FL(kc + 1);

    f32x4 sa[4];
    #pragma unroll
    for (int fn = 0; fn < 4; ++fn) sa[fn] = (f32x4){0.f,0.f,0.f,0.f};
    __builtin_amdgcn_s_setprio(1);
    #pragma unroll
    for (int fn = 0; fn < 4; ++fn){
      #pragma unroll
      for (int ds = 0; ds < 2; ++ds){
        bf8_t ah = *(const bf8_t*)&Khs[swz8(16*fn + c, g + 4*ds)];
        bf8_t al = *(const bf8_t*)&Kls[swz8(16*fn + c, g + 4*ds)];
        sa[fn] = MFMA16(ah, qh[ds], sa[fn]);   // 3-term split
        sa[fn] = MFMA16(al, qh[ds], sa[fn]);
        sa[fn] = MFMA16(ah, ql[ds], sa[fn]);
      }
    }
    __builtin_amdgcn_s_setprio(0);

    float x[4][4];
    float pmax = -1e30f;
    #pragma unroll
    for (int fn = 0; fn < 4; ++fn)
      #pragma unroll
      for (int r = 0; r < 4; ++r){
        x[fn][r] = sa[fn][r] * tsc2;
        pmax = fmaxf(pmax, x[fn][r]);
      }
    pmax = fmaxf(pmax, __shfl_xor(pmax, 16, 64));
    pmax = fmaxf(pmax, __shfl_xor(pmax, 32, 64));

    if (!__all(pmax <= m + 30.f)){       // defer-max: fires ~once (kc=0)
      float mn = fmaxf(m, pmax);
      float sc = exp2f(m - mn);
      m = mn;
      l *= sc;
      Ls[w][c] = sc;
      #pragma unroll
      for (int r = 0; r < 4; ++r){
        float so = Ls[w][4*g + r];
        #pragma unroll
        for (int fn = 0; fn < 4; ++fn) o[fn][r] *= so;
      }
    }

    float lsum = 0.f;
    #pragma unroll
    for (int fn = 0; fn < 4; ++fn){
      float e0 = exp2f(x[fn][0] - m);
      float e1 = exp2f(x[fn][1] - m);
      float e2 = exp2f(x[fn][2] - m);
      float e3 = exp2f(x[fn][3] - m);
      lsum += (e0 + e1) + (e2 + e3);
      uint2 pk;
      pk.x = pk2(e0, e1);
      pk.y = pk2(e2, e3);
      const int q4 = 4*fn + g;
      const int addr = (16*w + c)*64 + ((((q4 >> 1) ^ (c & 7)) << 3)) + (q4 & 1)*4;
      *(uint2*)&Ps[addr] = pk;
    }
    lsum += __shfl_xor(lsum, 16, 64);
    lsum += __shfl_xor(lsum, 32, 64);
    l += lsum;

    __builtin_amdgcn_s_setprio(1);
    #pragma unroll
    for (int kvs = 0; kvs < 2; ++kvs){
      bf8_t pa = *(const bf8_t*)&Ps[swz8(16*w + c, g + 4*kvs)];
      #pragma unroll
      for (int fn = 0; fn < 4; ++fn){
        bf8_t vb = *(const bf8_t*)&Vts[swz8(16*fn + c, g + 4*kvs)];
        o[fn] = MFMA16(pa, vb, o[fn]);
      }
    }
    __builtin_amdgcn_s_setprio(0);
    __syncthreads();
  }
  #undef ISSUE_FL

  Ls[w][c] = l;
  const int b = bh >> 4, hd = bh & 15;
  #pragma unroll
  for (int r = 0; r < 4; ++r){
    float linv = 1.f / Ls[w][4*g + r];
    const int q = q0 + 16*w + 4*g + r;
    #pragma unroll
    for (int fn = 0; fn < 4; ++fn)
      aout[((size_t)(b*SS + q))*DM + hd*DKH + 16*fn + c] = f2bf(o[fn][r] * linv);
  }
}

extern "C" void kernel_launch(void* const* d_in, const int* in_sizes, int n_in,
                              void* d_out, int out_size, void* d_ws, size_t ws_size,
                              hipStream_t stream)
{
  const float* query = (const float*)d_in[0];
  const float* key   = (const float*)d_in[1];
  const float* value = (const float*)d_in[2];
  const float* Wq = (const float*)d_in[3];
  const float* bq = (const float*)d_in[4];
  const float* Wk = (const float*)d_in[5];
  const float* bk = (const float*)d_in[6];
  const float* Wv = (const float*)d_in[7];
  const float* bv = (const float*)d_in[8];
  const float* Wo = (const float*)d_in[9];
  const float* bo = (const float*)d_in[10];
  const float* Wt1 = (const float*)d_in[11];
  const float* bt1 = (const float*)d_in[12];
  const float* Wt2 = (const float*)d_in[13];
  const float* bt2 = (const float*)d_in[14];

  const size_t E = (size_t)NB*SS*DM;       // 4,194,304
  const size_t WE = (size_t)DM*DM;

  uint32* Qi  = (uint32*)d_ws;             // E uint32 (hi|lo interleaved)
  uint32* Ki  = Qi + E;                    // E uint32
  ush* Vtb = (ush*)(Ki + E);               // E ush (b*16+h, dk, s)
  ush* Aob = Vtb + E;                      // E ush  -- also aliased as xqb
  ush* xqb = Aob;                          // alias: consumed before Aob written
  ush* xkb = Aob + E;
  ush* xvb = xkb + E;
  ush* Wqh = xvb + E;
  ush* Wql = Wqh + WE;
  ush* Wkh = Wql + WE;
  ush* Wkl = Wkh + WE;
  ush* Wvh = Wkl + WE;
  ush* Wvl = Wvh + WE;
  ush* Woh = Wvl + WE;
  float* stats = (float*)(Woh + WE);
  float* tws   = stats + 4*NBH;

  hipMemsetAsync(stats, 0, 4*NBH*sizeof(float), stream);

  xconv<<<dim3(2048, 3), 256, 0, stream>>>(query, key, value, xqb, xkb, xvb);

  dim3 wb(32, 8), wg(32, 32, 4);
  wconv4<<<wg, wb, 0, stream>>>(Wq, Wk, Wv, Wo, Wqh, Wkh, Wvh, Woh, Wql, Wkl, Wvl);

  proj_qkv<<<768, 256, 0, stream>>>(xqb, xkb, xvb,
      Wqh, Wql, Wkh, Wkl, Wvh, Wvl, bq, bk, bv, Qi, Ki, Vtb);

  attn_stats_mfma<<<1024, 256, 0, stream>>>(Qi, Ki, stats);
  time_mlp<<<1, 64, 0, stream>>>(stats, Wt1, bt1, Wt2, bt2, tws);
  attn_flash_mfma<<<1024, 256, 0, stream>>>(Qi, Ki, Vtb, tws, Aob);

  gemm_out<<<512, 256, 0, stream>>>(Aob, Woh, bo, (float*)d_out);
}